// Round 10
// baseline (243.531 us; speedup 1.0000x reference)
//
#include <hip/hip_runtime.h>

// StandGCN2: 2-layer GCN, N=100000, E=600000, 128->128(relu)->64, bf16 I/O.
// R10: pre-scaled features kill per-edge dinv. gemm1 writes hs = (x@W1)*dinv[row];
// fusedB computes h1=relu(di*(sum hs)+b1), g=h1@W2, writes gs=g*di; agg2 sums gs.
// sp = bare int src (4B scatter, 2.4MB L2-resident); fill chain = dst->atomic->store.
// Pipeline: prep -> count -> scan1 -> scan23 -> fill -> gemm1 -> fusedB -> agg2.

typedef unsigned short u16;
typedef unsigned int u32;
typedef __attribute__((ext_vector_type(8))) short bf16x8;
typedef __attribute__((ext_vector_type(4))) float f32x4;

__device__ __forceinline__ float b2f(u16 s) {
  return __uint_as_float(((u32)s) << 16);
}
__device__ __forceinline__ u16 f2b(float f) {
  u32 u = __float_as_uint(f);
  u32 r = (u + 0x7FFFu + ((u >> 16) & 1u)) >> 16;
  return (u16)r;
}
__device__ __forceinline__ u32 pk2(float a, float b) {
  return (u32)f2b(a) | ((u32)f2b(b) << 16);
}
__device__ __forceinline__ void dec8(uint4 v, float f[8]) {
  f[0] = __uint_as_float(v.x << 16);
  f[1] = __uint_as_float(v.x & 0xFFFF0000u);
  f[2] = __uint_as_float(v.y << 16);
  f[3] = __uint_as_float(v.y & 0xFFFF0000u);
  f[4] = __uint_as_float(v.z << 16);
  f[5] = __uint_as_float(v.z & 0xFFFF0000u);
  f[6] = __uint_as_float(v.w << 16);
  f[7] = __uint_as_float(v.w & 0xFFFF0000u);
}
__device__ __forceinline__ void fma8(uint4 v, float d, float acc[8]) {
  acc[0] = fmaf(__uint_as_float(v.x << 16), d, acc[0]);
  acc[1] = fmaf(__uint_as_float(v.x & 0xFFFF0000u), d, acc[1]);
  acc[2] = fmaf(__uint_as_float(v.y << 16), d, acc[2]);
  acc[3] = fmaf(__uint_as_float(v.y & 0xFFFF0000u), d, acc[3]);
  acc[4] = fmaf(__uint_as_float(v.z << 16), d, acc[4]);
  acc[5] = fmaf(__uint_as_float(v.z & 0xFFFF0000u), d, acc[5]);
  acc[6] = fmaf(__uint_as_float(v.w << 16), d, acc[6]);
  acc[7] = fmaf(__uint_as_float(v.w & 0xFFFF0000u), d, acc[7]);
}

// ---- prep: zero cnt + block-local dtype probe + weight convert ----

__global__ __launch_bounds__(256) void prep_k(const void* __restrict__ W1,
                                              const void* __restrict__ b1,
                                              const void* __restrict__ W2,
                                              const void* __restrict__ b2,
                                              u16* __restrict__ W1b, u16* __restrict__ ob1,
                                              u16* __restrict__ W2t, u16* __restrict__ ob2,
                                              int* __restrict__ mode,
                                              int* __restrict__ cnt, int np) {
  __shared__ int cnt_s;
  const int tid = threadIdx.x;
  int i = blockIdx.x * 256 + tid;
  if (i < np) cnt[i] = 0;

  if (tid == 0) cnt_s = 0;
  __syncthreads();
  int c = 0;
  for (int j = tid; j < 4096; j += 256) {
    u32 e = (((const u16*)W1)[j] >> 7) & 0xFFu;
    if (e >= 100u && e <= 130u) c++;
  }
  atomicAdd(&cnt_s, c);
  __syncthreads();
  const int m = (cnt_s < 3328) ? 1 : 0;  // 1 = fp32
  if (blockIdx.x == 0 && tid == 0) *mode = m;

  if (i < 24768) {
    int j = i;
    const void* src;
    u16* dst;
    int sidx, didx;
    if (j < 16384) {
      src = W1; dst = W1b; sidx = j; didx = j;  // plain copy
    } else if ((j -= 16384) < 128) {
      src = b1; dst = ob1; sidx = j; didx = j;
    } else if ((j -= 128) < 8192) {
      int nn = j >> 7, k = j & 127;               // W2t[n][k] = W2[k][n]
      src = W2; dst = W2t; sidx = k * 64 + nn; didx = j;
    } else {
      j -= 8192;
      src = b2; dst = ob2; sidx = j; didx = j;
    }
    dst[didx] = m ? f2b(((const float*)src)[sidx]) : ((const u16*)src)[sidx];
  }
}

// ---------------- CSR build ----------------

__global__ __launch_bounds__(256) void count_k(const int* __restrict__ dst,
                                               int* __restrict__ cnt, int E) {
  int e = blockIdx.x * 256 + threadIdx.x;
  if (e < E) atomicAdd(&cnt[dst[e]], 1);
}

__global__ __launch_bounds__(256) void scan1(const int* __restrict__ cnt,
                                             int* __restrict__ offs,
                                             int* __restrict__ bsum, int np) {
  __shared__ int lds[256];
  int t = threadIdx.x;
  int i = blockIdx.x * 256 + t;
  int v = cnt[i];
  lds[t] = v;
  __syncthreads();
#pragma unroll
  for (int off = 1; off < 256; off <<= 1) {
    int add = (t >= off) ? lds[t - off] : 0;
    __syncthreads();
    lds[t] += add;
    __syncthreads();
  }
  offs[i] = lds[t] - v;
  if (t == 0) bsum[blockIdx.x] = lds[255];
}

__global__ __launch_bounds__(256) void scan23(const int* __restrict__ offs,
                                              const int* __restrict__ bsum,
                                              int* __restrict__ cursor,
                                              const int* __restrict__ cnt,
                                              float* __restrict__ dinv,
                                              int4* __restrict__ ninfo, int np) {
  __shared__ int lds[256];
  const int t = threadIdx.x, b = blockIdx.x;
  int part = 0;
  for (int k = t; k < b; k += 256) part += bsum[k];
  lds[t] = part;
  __syncthreads();
#pragma unroll
  for (int off = 128; off > 0; off >>= 1) {
    if (t < off) lds[t] += lds[t + off];
    __syncthreads();
  }
  const int pre = lds[0];
  int i = b * 256 + t;
  int o = offs[i] + pre;
  cursor[i] = o;
  int c = cnt[i];
  float dv = rsqrtf((float)c + 1.0f);  // +1 self-loop
  dinv[i] = dv;
  ninfo[i] = make_int4(o, c, __float_as_int(dv), 0);
}

// 2 edges/thread for chain ILP; store bare src (4B)
__global__ __launch_bounds__(256) void fill_k(const int* __restrict__ src,
                                              const int* __restrict__ dst,
                                              int* __restrict__ cursor,
                                              int* __restrict__ sp, int E) {
  int e0 = blockIdx.x * 512 + threadIdx.x;
  int e1 = e0 + 256;
  int s0 = 0, s1 = 0, d0 = 0, d1 = 0;
  bool v0 = e0 < E, v1 = e1 < E;
  if (v0) { s0 = src[e0]; d0 = dst[e0]; }
  if (v1) { s1 = src[e1]; d1 = dst[e1]; }
  int p0 = 0, p1 = 0;
  if (v0) p0 = atomicAdd(&cursor[d0], 1);
  if (v1) p1 = atomicAdd(&cursor[d1], 1);
  if (v0) sp[p0] = s0;
  if (v1) sp[p1] = s1;
}

// ---------------- gemm1: hs = (x @ W1) * dinv[row] ----------------
// Layouts (m89/m91): A[m=lane&15][k=(lane>>4)*8+j]; C/D col=lane&15, row=(lane>>4)*4+reg.

__global__ __launch_bounds__(256) void gemm1_k(const void* __restrict__ Araw,
                                               const u16* __restrict__ W,
                                               const float* __restrict__ dinv,
                                               u16* __restrict__ out, int M,
                                               const int* __restrict__ mode) {
  __shared__ __align__(16) u16 Wt[128 * 136];
  __shared__ __align__(16) u16 As[64 * 136];
  const int tid = threadIdx.x;
  const int mcv = *mode;

  for (int idx = tid; idx < 128 * 128; idx += 256) {
    int n = idx & 127;
    int k = idx >> 7;
    Wt[n * 136 + k] = W[k * 128 + n];
  }
  __syncthreads();

  const int wv = tid >> 6, lane = tid & 63, lr = lane & 15, lq = lane >> 4;
  const int ntiles = (M + 63) >> 6;

  for (int t = blockIdx.x; t < ntiles; t += gridDim.x) {
    const int r0 = t * 64;
    __syncthreads();
    for (int idx = tid; idx < 64 * 16; idx += 256) {
      int row = idx >> 4, c = idx & 15;
      uint4 v = make_uint4(0u, 0u, 0u, 0u);
      if (r0 + row < M) {
        if (mcv) {
          const float* xf = (const float*)Araw + (size_t)(r0 + row) * 128 + c * 8;
          float4 f0 = *(const float4*)xf;
          float4 f1 = *(const float4*)(xf + 4);
          v.x = pk2(f0.x, f0.y);
          v.y = pk2(f0.z, f0.w);
          v.z = pk2(f1.x, f1.y);
          v.w = pk2(f1.z, f1.w);
        } else {
          v = *(const uint4*)((const u16*)Araw + (size_t)(r0 + row) * 128 + c * 8);
        }
      }
      *(uint4*)&As[row * 136 + c * 8] = v;
    }
    __syncthreads();

    bf16x8 a[4];
#pragma unroll
    for (int s = 0; s < 4; ++s)
      a[s] = *(const bf16x8*)&As[(wv * 16 + lr) * 136 + s * 32 + lq * 8];

    // per-output-row dinv (4 rows of this wave's C fragment)
    float dv[4];
#pragma unroll
    for (int r = 0; r < 4; ++r) {
      int row = r0 + wv * 16 + lq * 4 + r;
      dv[r] = (row < M) ? dinv[row] : 0.f;
    }

#pragma unroll
    for (int nt = 0; nt < 8; ++nt) {
      f32x4 acc = {0.f, 0.f, 0.f, 0.f};
#pragma unroll
      for (int s = 0; s < 4; ++s) {
        bf16x8 b = *(const bf16x8*)&Wt[(nt * 16 + lr) * 136 + s * 32 + lq * 8];
        acc = __builtin_amdgcn_mfma_f32_16x16x32_bf16(a[s], b, acc, 0, 0, 0);
      }
#pragma unroll
      for (int r = 0; r < 4; ++r) {
        int row = r0 + wv * 16 + lq * 4 + r;
        if (row < M) out[(size_t)row * 128 + nt * 16 + lr] = f2b(acc[r] * dv[r]);
      }
    }
  }
}

// ---- fusedB: gather hs (16 nodes/block, quarter-wave, unroll-4, no per-edge dinv)
//      -> h1 = relu(di*sum + b1) -> LDS -> MFMA W2t -> gs = g*di ----

__global__ __launch_bounds__(256) void fusedB_k(const u16* __restrict__ hs,
                                                const int* __restrict__ sp,
                                                const int4* __restrict__ ninfo,
                                                const u16* __restrict__ b1,
                                                const u16* __restrict__ W2t,
                                                u16* __restrict__ gs, int n) {
  __shared__ __align__(16) u16 As[16 * 136];
  const int tid = threadIdx.x, wv = tid >> 6, lane = tid & 63;
  const int lq = lane >> 4, lr = lane & 15;
  const int base = blockIdx.x * 16;
  const int i = base + wv * 4 + lq;
  const bool valid = (i < n);

  int start = 0, c = 0;
  float di = 0.f;
  if (valid) {
    int4 ni = ninfo[i];
    start = ni.x;
    c = ni.y;
    di = __int_as_float(ni.z);
  }
  float acc[8];
  {
    // self term: hs[i] = h[i]*di
    uint4 v = valid ? *(const uint4*)(hs + (size_t)i * 128 + lr * 8)
                    : make_uint4(0u, 0u, 0u, 0u);
    dec8(v, acc);
  }
  const int bl = lq * 16;
  for (int bs = 0; __any(bs < c); bs += 16) {
    int m = c - bs;
    m = m < 0 ? 0 : (m > 16 ? 16 : m);
    int s = 0;
    if (lr < m) s = sp[start + bs + lr];
    int mmw = m;
    mmw = max(mmw, __shfl_xor(mmw, 16));
    mmw = max(mmw, __shfl_xor(mmw, 32));
    for (int e = 0; e < mmw; e += 4) {
      int s0 = __shfl(s, bl + e), s1 = __shfl(s, bl + e + 1);
      int s2 = __shfl(s, bl + e + 2), s3 = __shfl(s, bl + e + 3);
      float w0 = (e < m) ? 1.f : 0.f;
      float w1 = (e + 1 < m) ? 1.f : 0.f;
      float w2 = (e + 2 < m) ? 1.f : 0.f;
      float w3 = (e + 3 < m) ? 1.f : 0.f;
      uint4 v0 = *(const uint4*)(hs + (size_t)s0 * 128 + lr * 8);
      uint4 v1 = *(const uint4*)(hs + (size_t)s1 * 128 + lr * 8);
      uint4 v2 = *(const uint4*)(hs + (size_t)s2 * 128 + lr * 8);
      uint4 v3 = *(const uint4*)(hs + (size_t)s3 * 128 + lr * 8);
      fma8(v0, w0, acc);
      fma8(v1, w1, acc);
      fma8(v2, w2, acc);
      fma8(v3, w3, acc);
    }
  }
  // h1 = relu(di*acc + b1) -> As tile (bf16)
  {
    uint4 bv = *(const uint4*)(b1 + lr * 8);
    float bf[8];
    dec8(bv, bf);
    float o[8];
#pragma unroll
    for (int j = 0; j < 8; ++j) o[j] = fmaxf(fmaf(acc[j], di, bf[j]), 0.f);
    uint4 ov;
    ov.x = pk2(o[0], o[1]);
    ov.y = pk2(o[2], o[3]);
    ov.z = pk2(o[4], o[5]);
    ov.w = pk2(o[6], o[7]);
    *(uint4*)&As[(wv * 4 + lq) * 136 + lr * 8] = ov;
  }
  __syncthreads();

  // W2 MFMA: wave wv -> col tile wv; epilogue scales by dinv[row]
  bf16x8 a[4];
#pragma unroll
  for (int s = 0; s < 4; ++s)
    a[s] = *(const bf16x8*)&As[lr * 136 + s * 32 + lq * 8];
  {
    const int nt = wv;
    f32x4 acc4 = {0.f, 0.f, 0.f, 0.f};
#pragma unroll
    for (int s = 0; s < 4; ++s) {
      bf16x8 b = *(const bf16x8*)&W2t[(nt * 16 + lr) * 128 + s * 32 + lq * 8];
      acc4 = __builtin_amdgcn_mfma_f32_16x16x32_bf16(a[s], b, acc4, 0, 0, 0);
    }
#pragma unroll
    for (int r = 0; r < 4; ++r) {
      int row = base + lq * 4 + r;
      if (row < n) {
        float dv = __int_as_float(((const int4*)ninfo)[row].z);
        gs[(size_t)row * 64 + nt * 16 + lr] = f2b(acc4[r] * dv);
      }
    }
  }
}

// ---- agg2: oct-wave over gs, 8 nodes/wave, unroll-4, no per-edge dinv ----

__global__ __launch_bounds__(256) void agg2_k(const u16* __restrict__ gs,
                                              const int* __restrict__ sp,
                                              const int4* __restrict__ ninfo,
                                              const u16* __restrict__ b2,
                                              void* __restrict__ outv, int n,
                                              const int* __restrict__ mode) {
  const int lane = threadIdx.x & 63;
  const int o8 = lane >> 3, l8 = lane & 7;
  const int i = blockIdx.x * 32 + (threadIdx.x >> 6) * 8 + o8;
  const bool valid = (i < n);

  int start = 0, c = 0;
  float di = 0.f;
  if (valid) {
    int4 ni = ninfo[i];
    start = ni.x;
    c = ni.y;
    di = __int_as_float(ni.z);
  }
  float acc[8];
  {
    uint4 v = valid ? *(const uint4*)(gs + (size_t)i * 64 + l8 * 8)
                    : make_uint4(0u, 0u, 0u, 0u);
    dec8(v, acc);  // self term gs[i]
  }
  const int bl = o8 * 8;
  for (int base = 0; __any(base < c); base += 8) {
    int m = c - base;
    m = m < 0 ? 0 : (m > 8 ? 8 : m);
    int s = 0;
    if (l8 < m) s = sp[start + base + l8];
    int mmw = m;
    mmw = max(mmw, __shfl_xor(mmw, 8));
    mmw = max(mmw, __shfl_xor(mmw, 16));
    mmw = max(mmw, __shfl_xor(mmw, 32));
    for (int e = 0; e < mmw; e += 4) {
      int s0 = __shfl(s, bl + e), s1 = __shfl(s, bl + e + 1);
      int s2 = __shfl(s, bl + e + 2), s3 = __shfl(s, bl + e + 3);
      float w0 = (e < m) ? 1.f : 0.f;
      float w1 = (e + 1 < m) ? 1.f : 0.f;
      float w2 = (e + 2 < m) ? 1.f : 0.f;
      float w3 = (e + 3 < m) ? 1.f : 0.f;
      uint4 v0 = *(const uint4*)(gs + (size_t)s0 * 64 + l8 * 8);
      uint4 v1 = *(const uint4*)(gs + (size_t)s1 * 64 + l8 * 8);
      uint4 v2 = *(const uint4*)(gs + (size_t)s2 * 64 + l8 * 8);
      uint4 v3 = *(const uint4*)(gs + (size_t)s3 * 64 + l8 * 8);
      fma8(v0, w0, acc);
      fma8(v1, w1, acc);
      fma8(v2, w2, acc);
      fma8(v3, w3, acc);
    }
  }
  if (valid) {
    uint4 bv = *(const uint4*)(b2 + l8 * 8);
    float bf[8];
    dec8(bv, bf);
    float o[8];
#pragma unroll
    for (int j = 0; j < 8; ++j) o[j] = fmaf(acc[j], di, bf[j]);
    if (*mode) {
      float* op = (float*)outv + (size_t)i * 64 + l8 * 8;
      *(float4*)op = make_float4(o[0], o[1], o[2], o[3]);
      *(float4*)(op + 4) = make_float4(o[4], o[5], o[6], o[7]);
    } else {
      uint4 ov;
      ov.x = pk2(o[0], o[1]);
      ov.y = pk2(o[2], o[3]);
      ov.z = pk2(o[4], o[5]);
      ov.w = pk2(o[6], o[7]);
      *(uint4*)((u16*)outv + (size_t)i * 64 + l8 * 8) = ov;
    }
  }
}

// ================= launch =================

extern "C" void kernel_launch(void* const* d_in, const int* in_sizes, int n_in,
                              void* d_out, int out_size, void* d_ws, size_t ws_size,
                              hipStream_t stream) {
  const void* x_raw  = d_in[0];
  const int*  ei     = (const int*)d_in[1];
  const void* W1_raw = d_in[2];
  const void* b1_raw = d_in[3];
  const void* W2_raw = d_in[4];
  const void* b2_raw = d_in[5];

  const int N = in_sizes[0] / 128;
  const int E = in_sizes[1] / 2;
  const int NP = ((N + 255) / 256) * 256;
  const int NB = NP / 256;

  char* ws = (char*)d_ws;
  size_t off = 0;
  auto alloc = [&](size_t bytes) -> void* {
    void* p = ws + off;
    off = (off + bytes + 255) & ~(size_t)255;
    return p;
  };
  int*   mode   = (int*)alloc(4);
  int*   cnt    = (int*)alloc((size_t)NP * 4);
  float* dinv   = (float*)alloc((size_t)NP * 4);
  int*   offs   = (int*)alloc((size_t)NP * 4);
  int*   cursor = (int*)alloc((size_t)NP * 4);
  int*   bsum   = (int*)alloc(1024 * 4);
  int4*  ninfo  = (int4*)alloc((size_t)NP * 16);
  int*   sp     = (int*)alloc((size_t)E * 4);
  u16*   W1b    = (u16*)alloc((size_t)128 * 128 * 2);
  u16*   b1b    = (u16*)alloc(128 * 2);
  u16*   W2t    = (u16*)alloc((size_t)64 * 128 * 2);
  u16*   b2b    = (u16*)alloc(64 * 2);
  u16*   hs     = (u16*)alloc((size_t)N * 128 * 2);
  u16*   gs     = (u16*)alloc((size_t)N * 64 * 2);

  const int eb = (E + 255) / 256;
  prep_k<<<NB, 256, 0, stream>>>(W1_raw, b1_raw, W2_raw, b2_raw,
                                 W1b, b1b, W2t, b2b, mode, cnt, NP);
  count_k<<<eb, 256, 0, stream>>>(ei + E, cnt, E);
  scan1<<<NB, 256, 0, stream>>>(cnt, offs, bsum, NP);
  scan23<<<NB, 256, 0, stream>>>(offs, bsum, cursor, cnt, dinv, ninfo, NP);
  fill_k<<<(E + 511) / 512, 256, 0, stream>>>(ei, ei + E, cursor, sp, E);
  gemm1_k<<<512, 256, 0, stream>>>(x_raw, W1b, dinv, hs, N, mode);
  fusedB_k<<<(N + 15) / 16, 256, 0, stream>>>(hs, sp, ninfo, b1b, W2t, gs, N);
  agg2_k<<<(N + 31) / 32, 256, 0, stream>>>(gs, sp, ninfo, b2b, d_out, N, mode);
}